// Round 13
// baseline (213.381 us; speedup 1.0000x reference)
//
#include <hip/hip_runtime.h>

// ---------------------------------------------------------------------------
// LearnableCurvGCN, round 12: degree-sorted gather scheduling.
//
// R12 counters: gather<128> pinned at 71us / FETCH 191MB / 39% / VALU 27%
// across 3 rounds. Discriminating experiment: waves currently serve 4 (or 8)
// nodes of iid Poisson(16) degree -> run to the max (E[max4]~20, ~20% idle
// issue; ~26% for gather<64>). Add a counting sort of nodes by degree
// (perm[]); gathers process nodes in degree order -> uniform waves.
// Traffic identical, per-node math identical, output bit-identical.
//   - helps  -> divergence was the gap (predict 71->~57, 36->~27)
//   - null   -> gathers are at the random-access LLC floor -> roofline.
//
// Pipeline:
//   k_hist -> k_scan_buckets -> k_colscan -> k_partition -> k_bucket_sort
//   k_deghist -> k_degscan -> k_degplace            (new, ~5us)
//   gemm1(fp32 x) -> gather1(perm) -> gemm2 -> gather2(perm)
// ---------------------------------------------------------------------------

constexpr int N_NODES = 100000;
constexpr int N_EDGES = 1600000;
constexpr int IN_DIM  = 128;
constexpr int HID_DIM = 128;
constexpr int OUT_DIM = 64;

constexpr int RANGE = 256;                            // nodes per bucket
constexpr int NBUK  = (N_NODES + RANGE - 1) / RANGE;  // 391
constexpr int EPB   = 8192;                           // edges per partition block
constexpr int NPART = (N_EDGES + EPB - 1) / EPB;      // 196
constexpr int STAGE_CAP = 6144;                       // bucket edges LDS cap (48KB)
constexpr int DBINS = 128;                            // degree bins (clamp)

using bf16x8 = __attribute__((ext_vector_type(8))) short;
using f32x4  = __attribute__((ext_vector_type(4))) float;

// --- helpers -----------------------------------------------------------------
__device__ __forceinline__ unsigned short f2b(float f)
{
    unsigned int u = __float_as_uint(f);
    u += 0x7fffu + ((u >> 16) & 1u);     // round-to-nearest-even
    return (unsigned short)(u >> 16);
}

__device__ __forceinline__ float edge_weight_mlp(float c,
                                                 const float* __restrict__ mw1,
                                                 const float* __restrict__ mb1,
                                                 const float* __restrict__ mw2,
                                                 const float* __restrict__ mb2)
{
    float z = mb2[0];
#pragma unroll
    for (int i = 0; i < 16; ++i) {
        float h = fmaf(c, mw1[i], mb1[i]);
        h = fmaxf(h, 0.0f);
        z = fmaf(h, mw2[i], z);
    }
    float s = 1.0f / (1.0f + __expf(-z));
    return fmaf(0.9f, s, 0.1f);
}

// --- 1. coarse histogram: blockHist[bucket][block] (bucket-major), gcnt -------
__global__ __launch_bounds__(512) void k_hist(const int* __restrict__ dst,
                                              int* __restrict__ blockHist,
                                              int* __restrict__ gcnt)
{
    __shared__ int hist[NBUK];
    const int tid = threadIdx.x;
    const int b   = blockIdx.x;
    for (int i = tid; i < NBUK; i += 512) hist[i] = 0;
    __syncthreads();
    const int base = b * EPB;
    const int n = min(EPB, N_EDGES - base);
    for (int i = tid; i < n; i += 512)
        atomicAdd(&hist[dst[base + i] >> 8], 1);
    __syncthreads();
    for (int i = tid; i < NBUK; i += 512) {
        int h = hist[i];
        blockHist[(size_t)i * NPART + b] = h;
        if (h) atomicAdd(&gcnt[i], h);
    }
}

// --- 2. bucketBase = exclusive_scan(gcnt); bucketBase[NBUK] = total -----------
__global__ __launch_bounds__(512) void k_scan_buckets(const int* __restrict__ gcnt,
                                                      int* __restrict__ bucketBase)
{
    __shared__ int sm[512];
    const int t = threadIdx.x;
    int v = (t < NBUK) ? gcnt[t] : 0;
    sm[t] = v;
    __syncthreads();
#pragma unroll
    for (int o = 1; o < 512; o <<= 1) {
        int u = (t >= o) ? sm[t - o] : 0;
        __syncthreads();
        sm[t] += u;
        __syncthreads();
    }
    if (t < NBUK) bucketBase[t] = sm[t] - v;
    if (t == NBUK - 1) bucketBase[NBUK] = sm[t];
}

// --- 3. per-bucket scan of its NPART block counts (parallel, LDS) -------------
__global__ __launch_bounds__(256) void k_colscan(int* __restrict__ blockHist,
                                                 const int* __restrict__ bucketBase)
{
    const int j = blockIdx.x;
    const int t = threadIdx.x;
    __shared__ int sm[256];
    int v = (t < NPART) ? blockHist[(size_t)j * NPART + t] : 0;
    sm[t] = v;
    __syncthreads();
#pragma unroll
    for (int o = 1; o < 256; o <<= 1) {
        int u = (t >= o) ? sm[t - o] : 0;
        __syncthreads();
        sm[t] += u;
        __syncthreads();
    }
    if (t < NPART)
        blockHist[(size_t)j * NPART + t] = bucketBase[j] + sm[t] - v;
}

// --- 4. partition edges into coarse-bucket segments ----------------------------
__global__ __launch_bounds__(512) void k_partition(const float* __restrict__ curv,
                                                   const int*   __restrict__ src,
                                                   const int*   __restrict__ dst,
                                                   const float* __restrict__ mw1,
                                                   const float* __restrict__ mb1,
                                                   const float* __restrict__ mw2,
                                                   const float* __restrict__ mb2,
                                                   const int*   __restrict__ blockHist,
                                                   int2* __restrict__ ep_tmp)
{
    __shared__ int cur[NBUK];
    const int tid = threadIdx.x;
    const int b   = blockIdx.x;
    for (int i = tid; i < NBUK; i += 512)
        cur[i] = blockHist[(size_t)i * NPART + b];
    __syncthreads();
    const int base = b * EPB;
    const int n = min(EPB, N_EDGES - base);
    for (int i = tid; i < n; i += 512) {
        int e = base + i;
        int d = dst[e];
        float w = edge_weight_mlp(curv[e], mw1, mb1, mw2, mb2);
        int pos = atomicAdd(&cur[d >> 8], 1);
        int meta = src[e] | ((d & (RANGE - 1)) << 17);   // src<2^17, dl<256
        ep_tmp[pos] = make_int2(meta, __float_as_int(w));
    }
}

// --- 5. per-bucket counting sort + deg + dis + rp (LDS-staged) -----------------
__global__ __launch_bounds__(256) void k_bucket_sort(const int2* __restrict__ ep_tmp,
                                                     const int*  __restrict__ bucketBase,
                                                     int2* __restrict__ ep,
                                                     int*  __restrict__ rp,
                                                     float* __restrict__ dis)
{
    const int b   = blockIdx.x;
    const int tid = threadIdx.x;
    const int base  = bucketBase[b];
    const int nE    = bucketBase[b + 1] - base;
    const int node0 = b * RANGE;
    const int nNodes = min(RANGE, N_NODES - node0);

    __shared__ int2  stage[STAGE_CAP];     // 48KB
    __shared__ int   cnt[RANGE];
    __shared__ float deg[RANGE];
    __shared__ int   sm[RANGE];
    __shared__ int   cur[RANGE];

    const bool fit = (nE <= STAGE_CAP);

    cnt[tid] = 0;
    deg[tid] = 0.0f;
    __syncthreads();
    for (int i = tid; i < nE; i += 256) {
        int2 t = ep_tmp[base + i];
        if (fit) stage[i] = t;
        int dl = (t.x >> 17) & (RANGE - 1);
        atomicAdd(&cnt[dl], 1);
        atomicAdd(&deg[dl], __int_as_float(t.y));
    }
    __syncthreads();
    int c = cnt[tid];
    sm[tid] = c;
    __syncthreads();
#pragma unroll
    for (int o = 1; o < 256; o <<= 1) {
        int u = (tid >= o) ? sm[tid - o] : 0;
        __syncthreads();
        sm[tid] += u;
        __syncthreads();
    }
    int excl = sm[tid] - c;
    cur[tid] = base + excl;
    if (tid < nNodes) {
        rp[node0 + tid]  = base + excl;
        dis[node0 + tid] = rsqrtf(deg[tid] + 1.0f);
    }
    if (b == NBUK - 1 && tid == 0) rp[N_NODES] = N_EDGES;
    __syncthreads();
    for (int i = tid; i < nE; i += 256) {
        int2 t = fit ? stage[i] : ep_tmp[base + i];
        int dl = (t.x >> 17) & (RANGE - 1);
        int pos = atomicAdd(&cur[dl], 1);
        ep[pos] = make_int2(t.x & 0x1FFFF, t.y);       // (src, ew)
    }
}

// --- 6a. degree histogram (LDS-aggregated) -------------------------------------
__global__ __launch_bounds__(256) void k_deghist(const int* __restrict__ rp,
                                                 int* __restrict__ dhist)
{
    __shared__ int h[DBINS];
    const int tid = threadIdx.x;
    if (tid < DBINS) h[tid] = 0;
    __syncthreads();
    int n = blockIdx.x * 256 + tid;
    if (n < N_NODES) {
        int d = min(rp[n + 1] - rp[n], DBINS - 1);
        atomicAdd(&h[d], 1);
    }
    __syncthreads();
    if (tid < DBINS && h[tid]) atomicAdd(&dhist[tid], h[tid]);
}

// --- 6b. dbase = exclusive_scan(dhist) -----------------------------------------
__global__ __launch_bounds__(128) void k_degscan(const int* __restrict__ dhist,
                                                 int* __restrict__ dbase)
{
    __shared__ int sm[DBINS];
    const int t = threadIdx.x;
    int v = dhist[t];
    sm[t] = v;
    __syncthreads();
#pragma unroll
    for (int o = 1; o < DBINS; o <<= 1) {
        int u = (t >= o) ? sm[t - o] : 0;
        __syncthreads();
        sm[t] += u;
        __syncthreads();
    }
    dbase[t] = sm[t] - v;
}

// --- 6c. place nodes into perm, block-aggregated (low atomic contention) -------
__global__ __launch_bounds__(256) void k_degplace(const int* __restrict__ rp,
                                                  int* __restrict__ dbase,
                                                  int* __restrict__ perm)
{
    __shared__ int h[DBINS];
    __shared__ int base[DBINS];
    __shared__ int cur[DBINS];
    const int tid = threadIdx.x;
    if (tid < DBINS) h[tid] = 0;
    __syncthreads();
    int n = blockIdx.x * 256 + tid;
    int bin = -1;
    if (n < N_NODES) {
        bin = min(rp[n + 1] - rp[n], DBINS - 1);
        atomicAdd(&h[bin], 1);
    }
    __syncthreads();
    if (tid < DBINS) {
        base[tid] = h[tid] ? atomicAdd(&dbase[tid], h[tid]) : 0;
        cur[tid] = 0;
    }
    __syncthreads();
    if (n < N_NODES) {
        int off = atomicAdd(&cur[bin], 1);
        perm[base[bin] + off] = n;
    }
}

// --- prepack W into B-fragment layout (lane l: col=l&15, k-octet=l>>4) -----------
template <int KIN, int KOUT>
__global__ __launch_bounds__(256) void k_prepack(const float* __restrict__ W,
                                                 unsigned short* __restrict__ wp)
{
    constexpr int KS = KIN / 32;
    constexpr int NSLOT = (KOUT / 16) * KS * 64;
    int idx = blockIdx.x * blockDim.x + threadIdx.x;
    if (idx >= NSLOT) return;
    int l  = idx & 63;
    int t  = idx >> 6;
    int ks = t % KS;
    int nt = t / KS;
    int col = nt * 16 + (l & 15);
    int k0  = ks * 32 + (l >> 4) * 8;
    unsigned short o[8];
#pragma unroll
    for (int j = 0; j < 8; ++j)
        o[j] = f2b(W[(k0 + j) * KOUT + col]);
    *reinterpret_cast<uint4*>(&wp[(size_t)idx * 8]) = *reinterpret_cast<uint4*>(o);
}

// --- MFMA GEMM, dis-scaled epilogue; A either fp32 (in-reg cvt) or bf16 ---------
template <int KIN, int KOUT, bool AFP32>
__global__ __launch_bounds__(256) void k_gemm_mfma(const void* __restrict__ Aptr,
                                                   const unsigned short* __restrict__ Wp,
                                                   const float* __restrict__ dis,
                                                   unsigned short* __restrict__ C)
{
    constexpr int NT = KOUT / 16;
    constexpr int KS = KIN / 32;
    const int tid  = threadIdx.x;
    const int lane = tid & 63;
    const int wave = blockIdx.x * (blockDim.x >> 6) + (tid >> 6);
    const int row0 = wave * 16;
    if (row0 >= N_NODES) return;

    f32x4 acc[NT];
#pragma unroll
    for (int nt = 0; nt < NT; ++nt)
        acc[nt] = f32x4{0.f, 0.f, 0.f, 0.f};

    const int arow = row0 + (lane & 15);
    const int koff = (lane >> 4) * 8;
#pragma unroll
    for (int ks = 0; ks < KS; ++ks) {
        bf16x8 a;
        if constexpr (AFP32) {
            const float* A = (const float*)Aptr;
            const float* p = A + (size_t)arow * KIN + ks * 32 + koff;
            float4 f0 = *reinterpret_cast<const float4*>(p);
            float4 f1 = *reinterpret_cast<const float4*>(p + 4);
            a[0] = (short)f2b(f0.x); a[1] = (short)f2b(f0.y);
            a[2] = (short)f2b(f0.z); a[3] = (short)f2b(f0.w);
            a[4] = (short)f2b(f1.x); a[5] = (short)f2b(f1.y);
            a[6] = (short)f2b(f1.z); a[7] = (short)f2b(f1.w);
        } else {
            const unsigned short* A = (const unsigned short*)Aptr;
            a = *reinterpret_cast<const bf16x8*>(A + (size_t)arow * KIN + ks * 32 + koff);
        }
#pragma unroll
        for (int nt = 0; nt < NT; ++nt) {
            bf16x8 bfr = *reinterpret_cast<const bf16x8*>(Wp + ((size_t)(nt * KS + ks) * 64 + lane) * 8);
            acc[nt] = __builtin_amdgcn_mfma_f32_16x16x32_bf16(a, bfr, acc[nt], 0, 0, 0);
        }
    }

    // C/D layout (m89-verified): col = lane&15, row = (lane>>4)*4 + r
    const int r0 = row0 + ((lane >> 4) << 2);
    const int c0 = lane & 15;
    float dv[4];
#pragma unroll
    for (int r = 0; r < 4; ++r) dv[r] = dis[r0 + r];
#pragma unroll
    for (int nt = 0; nt < NT; ++nt) {
#pragma unroll
        for (int r = 0; r < 4; ++r)
            C[(size_t)(r0 + r) * KOUT + nt * 16 + c0] = f2b(acc[nt][r] * dv[r]);
    }
}

// --- CSR gather (degree-sorted perm), 16B loads, fused finalize ------------------
// out[n] = dis[n] * (sum_e ew_e * xws[src_e] + xws[n]) + b   (+relu / bf16 opt)
template <int DIM, bool RELU, bool OBF16>
__global__ __launch_bounds__(256) void k_gather(const int*  __restrict__ perm,
                                                const int*  __restrict__ rp,
                                                const int2* __restrict__ ep,
                                                const unsigned short* __restrict__ xws,
                                                const float* __restrict__ dis,
                                                const float* __restrict__ bias,
                                                void* __restrict__ out)
{
    constexpr int TPN = DIM / 8;          // threads per node (16 or 8)
    constexpr int NPB = 256 / TPN;        // nodes per block; N_NODES % NPB == 0
    const int tid = threadIdx.x;
    const int n   = perm[blockIdx.x * NPB + tid / TPN];
    const int d8  = tid % TPN;
    const uint4* xw8 = reinterpret_cast<const uint4*>(xws);
    const int beg = rp[n];
    const int end = rp[n + 1];

    float a0[8] = {0,0,0,0,0,0,0,0};
    float a1[8] = {0,0,0,0,0,0,0,0};

    auto fma8 = [](float w, uint4 u, float* acc) {
        acc[0] = fmaf(w, __uint_as_float(u.x << 16),          acc[0]);
        acc[1] = fmaf(w, __uint_as_float(u.x & 0xFFFF0000u),  acc[1]);
        acc[2] = fmaf(w, __uint_as_float(u.y << 16),          acc[2]);
        acc[3] = fmaf(w, __uint_as_float(u.y & 0xFFFF0000u),  acc[3]);
        acc[4] = fmaf(w, __uint_as_float(u.z << 16),          acc[4]);
        acc[5] = fmaf(w, __uint_as_float(u.z & 0xFFFF0000u),  acc[5]);
        acc[6] = fmaf(w, __uint_as_float(u.w << 16),          acc[6]);
        acc[7] = fmaf(w, __uint_as_float(u.w & 0xFFFF0000u),  acc[7]);
    };

    int i = beg;
    for (; i + 8 <= end; i += 8) {
        int2 e0 = ep[i],     e1 = ep[i + 1], e2 = ep[i + 2], e3 = ep[i + 3];
        int2 e4 = ep[i + 4], e5 = ep[i + 5], e6 = ep[i + 6], e7 = ep[i + 7];
        uint4 u0 = xw8[(size_t)e0.x * TPN + d8];
        uint4 u1 = xw8[(size_t)e1.x * TPN + d8];
        uint4 u2 = xw8[(size_t)e2.x * TPN + d8];
        uint4 u3 = xw8[(size_t)e3.x * TPN + d8];
        uint4 u4 = xw8[(size_t)e4.x * TPN + d8];
        uint4 u5 = xw8[(size_t)e5.x * TPN + d8];
        uint4 u6 = xw8[(size_t)e6.x * TPN + d8];
        uint4 u7 = xw8[(size_t)e7.x * TPN + d8];
        fma8(__int_as_float(e0.y), u0, a0);
        fma8(__int_as_float(e1.y), u1, a1);
        fma8(__int_as_float(e2.y), u2, a0);
        fma8(__int_as_float(e3.y), u3, a1);
        fma8(__int_as_float(e4.y), u4, a0);
        fma8(__int_as_float(e5.y), u5, a1);
        fma8(__int_as_float(e6.y), u6, a0);
        fma8(__int_as_float(e7.y), u7, a1);
    }
    for (; i < end; ++i) {
        int2 e = ep[i];
        uint4 u = xw8[(size_t)e.x * TPN + d8];
        fma8(__int_as_float(e.y), u, a0);
    }
    // self term: + 1.0 * xws[n]
    {
        uint4 un = xw8[(size_t)n * TPN + d8];
        fma8(1.0f, un, a0);
    }

    const float dn = dis[n];
    const float4* b4 = reinterpret_cast<const float4*>(bias);
    float4 blo = b4[d8 * 2];
    float4 bhi = b4[d8 * 2 + 1];
    float v[8];
    v[0] = fmaf(dn, a0[0] + a1[0], blo.x);
    v[1] = fmaf(dn, a0[1] + a1[1], blo.y);
    v[2] = fmaf(dn, a0[2] + a1[2], blo.z);
    v[3] = fmaf(dn, a0[3] + a1[3], blo.w);
    v[4] = fmaf(dn, a0[4] + a1[4], bhi.x);
    v[5] = fmaf(dn, a0[5] + a1[5], bhi.y);
    v[6] = fmaf(dn, a0[6] + a1[6], bhi.z);
    v[7] = fmaf(dn, a0[7] + a1[7], bhi.w);
    if (RELU) {
#pragma unroll
        for (int j = 0; j < 8; ++j) v[j] = fmaxf(v[j], 0.0f);
    }
    if (OBF16) {
        uint4 o;
        o.x = (unsigned)f2b(v[0]) | ((unsigned)f2b(v[1]) << 16);
        o.y = (unsigned)f2b(v[2]) | ((unsigned)f2b(v[3]) << 16);
        o.z = (unsigned)f2b(v[4]) | ((unsigned)f2b(v[5]) << 16);
        o.w = (unsigned)f2b(v[6]) | ((unsigned)f2b(v[7]) << 16);
        reinterpret_cast<uint4*>(out)[(size_t)n * TPN + d8] = o;
    } else {
        float4* o4 = reinterpret_cast<float4*>(out);
        o4[(size_t)n * (DIM / 4) + d8 * 2]     = make_float4(v[0], v[1], v[2], v[3]);
        o4[(size_t)n * (DIM / 4) + d8 * 2 + 1] = make_float4(v[4], v[5], v[6], v[7]);
    }
}

extern "C" void kernel_launch(void* const* d_in, const int* in_sizes, int n_in,
                              void* d_out, int out_size, void* d_ws, size_t ws_size,
                              hipStream_t stream)
{
    const float* x    = (const float*)d_in[0];
    const int*   eidx = (const int*)  d_in[1];   // [2, N_EDGES] int32
    const float* curv = (const float*)d_in[2];   // [N_EDGES, 1]
    const float* W1   = (const float*)d_in[3];
    const float* b1   = (const float*)d_in[4];
    const float* W2   = (const float*)d_in[5];
    const float* b2   = (const float*)d_in[6];
    const float* mw1  = (const float*)d_in[7];
    const float* mb1  = (const float*)d_in[8];
    const float* mw2  = (const float*)d_in[9];
    const float* mb2  = (const float*)d_in[10];

    const int* src = eidx;
    const int* dst = eidx + N_EDGES;
    float* out = (float*)d_out;

    // --- workspace carve-out (~79 MB) ---
    char*  ws  = (char*)d_ws;
    size_t off = 0;
    auto alloc = [&](size_t bytes) -> void* {
        void* p = ws + off;
        off += (bytes + 255) & ~(size_t)255;
        return p;
    };
    float* dis       = (float*)alloc(sizeof(float) * N_NODES);
    int*   rp        = (int*)  alloc(sizeof(int) * (N_NODES + 1));
    int*   gcnt      = (int*)  alloc(sizeof(int) * NBUK);                  // [zeroed]
    int*   dhist     = (int*)  alloc(sizeof(int) * DBINS);                 // [zeroed]
    int*   dbase     = (int*)  alloc(sizeof(int) * DBINS);
    int*   perm      = (int*)  alloc(sizeof(int) * N_NODES);
    int*   bucketBase= (int*)  alloc(sizeof(int) * (NBUK + 1));
    int*   blockHist = (int*)  alloc(sizeof(int) * (size_t)NBUK * NPART);  // bucket-major
    int2*  ep_tmp    = (int2*) alloc(sizeof(int2) * N_EDGES);
    int2*  ep        = (int2*) alloc(sizeof(int2) * N_EDGES);              // (src, ew)
    unsigned short* xws = (unsigned short*)alloc(sizeof(unsigned short) * (size_t)N_NODES * HID_DIM);
    unsigned short* h1b = (unsigned short*)alloc(sizeof(unsigned short) * (size_t)N_NODES * HID_DIM);
    unsigned short* wp1 = (unsigned short*)alloc(sizeof(unsigned short) * (HID_DIM / 16) * (IN_DIM / 32) * 64 * 8);
    unsigned short* wp2 = (unsigned short*)alloc(sizeof(unsigned short) * (OUT_DIM / 16) * (HID_DIM / 32) * 64 * 8);

    // zero gcnt + dhist (contiguous in the carve-out)
    hipMemsetAsync(gcnt, 0, (size_t)((char*)dbase - (char*)gcnt), stream);

    const int B = 256;
    auto cdiv = [](long long a, long long b) { return (int)((a + b - 1) / b); };

    // CSR build via bucketed counting sort (deg/dis fused into bucket sort)
    k_hist        <<<NPART, 512, 0, stream>>>(dst, blockHist, gcnt);
    k_scan_buckets<<<1, 512, 0, stream>>>(gcnt, bucketBase);
    k_colscan     <<<NBUK, 256, 0, stream>>>(blockHist, bucketBase);
    k_partition   <<<NPART, 512, 0, stream>>>(curv, src, dst, mw1, mb1, mw2, mb2,
                                              blockHist, ep_tmp);
    k_bucket_sort <<<NBUK, 256, 0, stream>>>(ep_tmp, bucketBase, ep, rp, dis);

    // degree-sorted node permutation (uniform waves in the gathers)
    k_deghist <<<cdiv(N_NODES, 256), 256, 0, stream>>>(rp, dhist);
    k_degscan <<<1, DBINS, 0, stream>>>(dhist, dbase);
    k_degplace<<<cdiv(N_NODES, 256), 256, 0, stream>>>(rp, dbase, perm);

    // weight prepack (tiny)
    k_prepack<IN_DIM, HID_DIM><<<cdiv((HID_DIM/16)*(IN_DIM/32)*64, B), B, 0, stream>>>(W1, wp1);
    k_prepack<HID_DIM, OUT_DIM><<<cdiv((OUT_DIM/16)*(HID_DIM/32)*64, B), B, 0, stream>>>(W2, wp2);

    const int GEMM_GRID = cdiv(N_NODES / 16, 4);   // 4 waves/block, 16 rows/wave

    // layer 1: xws1 = dis .* (x@W1)  (MFMA, fp32 A with in-reg cvt)
    k_gemm_mfma<IN_DIM, HID_DIM, true><<<GEMM_GRID, 256, 0, stream>>>(x, wp1, dis, xws);
    k_gather<HID_DIM, true, true><<<N_NODES / 16, 256, 0, stream>>>(perm, rp, ep, xws, dis, b1, h1b);

    // layer 2: xws2 = dis .* (h1@W2); out = dis*(gather+self) + b2  (fp32)
    k_gemm_mfma<HID_DIM, OUT_DIM, false><<<GEMM_GRID, 256, 0, stream>>>(h1b, wp2, dis, xws);
    k_gather<OUT_DIM, false, false><<<N_NODES / 32, 256, 0, stream>>>(perm, rp, ep, xws, dis, b2, out);
}

// Round 14
// 207.709 us; speedup vs baseline: 1.0273x; 1.0273x over previous
//
#include <hip/hip_runtime.h>

// ---------------------------------------------------------------------------
// LearnableCurvGCN, round 13: window-local degree sort (divergence fix
// WITHOUT the locality loss).
//
// R13 post-mortem: global degree sort = split verdict. Gather 71->66us
// (divergence real, ~7%) but FETCH 191->202MB (ep/out access order
// randomized, L2 reuse lost) + 8us build cost -> net +3us. Fix: sort nodes
// by degree only within 2048-node windows (one LDS counting-sort kernel,
// 49 blocks, ~3us). Wave uniformity is statistically identical (iid
// Poisson(16) within windows); ep/rp/out locality is that of the unsorted
// baseline.
//
// Pipeline:
//   k_hist -> k_scan_buckets -> k_colscan -> k_partition -> k_bucket_sort
//   k_wsort (window-local degree perm)
//   gemm1(fp32 x, MFMA) -> gather1(perm) -> gemm2 -> gather2(perm)
// ---------------------------------------------------------------------------

constexpr int N_NODES = 100000;
constexpr int N_EDGES = 1600000;
constexpr int IN_DIM  = 128;
constexpr int HID_DIM = 128;
constexpr int OUT_DIM = 64;

constexpr int RANGE = 256;                            // nodes per bucket
constexpr int NBUK  = (N_NODES + RANGE - 1) / RANGE;  // 391
constexpr int EPB   = 8192;                           // edges per partition block
constexpr int NPART = (N_EDGES + EPB - 1) / EPB;      // 196
constexpr int STAGE_CAP = 6144;                       // bucket edges LDS cap (48KB)
constexpr int WSIZE = 2048;                           // degree-sort window
constexpr int WBINS = 64;                             // degree bins (clamp)

using bf16x8 = __attribute__((ext_vector_type(8))) short;
using f32x4  = __attribute__((ext_vector_type(4))) float;

// --- helpers -----------------------------------------------------------------
__device__ __forceinline__ unsigned short f2b(float f)
{
    unsigned int u = __float_as_uint(f);
    u += 0x7fffu + ((u >> 16) & 1u);     // round-to-nearest-even
    return (unsigned short)(u >> 16);
}

__device__ __forceinline__ float edge_weight_mlp(float c,
                                                 const float* __restrict__ mw1,
                                                 const float* __restrict__ mb1,
                                                 const float* __restrict__ mw2,
                                                 const float* __restrict__ mb2)
{
    float z = mb2[0];
#pragma unroll
    for (int i = 0; i < 16; ++i) {
        float h = fmaf(c, mw1[i], mb1[i]);
        h = fmaxf(h, 0.0f);
        z = fmaf(h, mw2[i], z);
    }
    float s = 1.0f / (1.0f + __expf(-z));
    return fmaf(0.9f, s, 0.1f);
}

// --- 1. coarse histogram: blockHist[bucket][block] (bucket-major), gcnt -------
__global__ __launch_bounds__(512) void k_hist(const int* __restrict__ dst,
                                              int* __restrict__ blockHist,
                                              int* __restrict__ gcnt)
{
    __shared__ int hist[NBUK];
    const int tid = threadIdx.x;
    const int b   = blockIdx.x;
    for (int i = tid; i < NBUK; i += 512) hist[i] = 0;
    __syncthreads();
    const int base = b * EPB;
    const int n = min(EPB, N_EDGES - base);
    for (int i = tid; i < n; i += 512)
        atomicAdd(&hist[dst[base + i] >> 8], 1);
    __syncthreads();
    for (int i = tid; i < NBUK; i += 512) {
        int h = hist[i];
        blockHist[(size_t)i * NPART + b] = h;
        if (h) atomicAdd(&gcnt[i], h);
    }
}

// --- 2. bucketBase = exclusive_scan(gcnt); bucketBase[NBUK] = total -----------
__global__ __launch_bounds__(512) void k_scan_buckets(const int* __restrict__ gcnt,
                                                      int* __restrict__ bucketBase)
{
    __shared__ int sm[512];
    const int t = threadIdx.x;
    int v = (t < NBUK) ? gcnt[t] : 0;
    sm[t] = v;
    __syncthreads();
#pragma unroll
    for (int o = 1; o < 512; o <<= 1) {
        int u = (t >= o) ? sm[t - o] : 0;
        __syncthreads();
        sm[t] += u;
        __syncthreads();
    }
    if (t < NBUK) bucketBase[t] = sm[t] - v;
    if (t == NBUK - 1) bucketBase[NBUK] = sm[t];
}

// --- 3. per-bucket scan of its NPART block counts (parallel, LDS) -------------
__global__ __launch_bounds__(256) void k_colscan(int* __restrict__ blockHist,
                                                 const int* __restrict__ bucketBase)
{
    const int j = blockIdx.x;
    const int t = threadIdx.x;
    __shared__ int sm[256];
    int v = (t < NPART) ? blockHist[(size_t)j * NPART + t] : 0;
    sm[t] = v;
    __syncthreads();
#pragma unroll
    for (int o = 1; o < 256; o <<= 1) {
        int u = (t >= o) ? sm[t - o] : 0;
        __syncthreads();
        sm[t] += u;
        __syncthreads();
    }
    if (t < NPART)
        blockHist[(size_t)j * NPART + t] = bucketBase[j] + sm[t] - v;
}

// --- 4. partition edges into coarse-bucket segments ----------------------------
__global__ __launch_bounds__(512) void k_partition(const float* __restrict__ curv,
                                                   const int*   __restrict__ src,
                                                   const int*   __restrict__ dst,
                                                   const float* __restrict__ mw1,
                                                   const float* __restrict__ mb1,
                                                   const float* __restrict__ mw2,
                                                   const float* __restrict__ mb2,
                                                   const int*   __restrict__ blockHist,
                                                   int2* __restrict__ ep_tmp)
{
    __shared__ int cur[NBUK];
    const int tid = threadIdx.x;
    const int b   = blockIdx.x;
    for (int i = tid; i < NBUK; i += 512)
        cur[i] = blockHist[(size_t)i * NPART + b];
    __syncthreads();
    const int base = b * EPB;
    const int n = min(EPB, N_EDGES - base);
    for (int i = tid; i < n; i += 512) {
        int e = base + i;
        int d = dst[e];
        float w = edge_weight_mlp(curv[e], mw1, mb1, mw2, mb2);
        int pos = atomicAdd(&cur[d >> 8], 1);
        int meta = src[e] | ((d & (RANGE - 1)) << 17);   // src<2^17, dl<256
        ep_tmp[pos] = make_int2(meta, __float_as_int(w));
    }
}

// --- 5. per-bucket counting sort + deg + dis + rp (LDS-staged) -----------------
__global__ __launch_bounds__(256) void k_bucket_sort(const int2* __restrict__ ep_tmp,
                                                     const int*  __restrict__ bucketBase,
                                                     int2* __restrict__ ep,
                                                     int*  __restrict__ rp,
                                                     float* __restrict__ dis)
{
    const int b   = blockIdx.x;
    const int tid = threadIdx.x;
    const int base  = bucketBase[b];
    const int nE    = bucketBase[b + 1] - base;
    const int node0 = b * RANGE;
    const int nNodes = min(RANGE, N_NODES - node0);

    __shared__ int2  stage[STAGE_CAP];     // 48KB
    __shared__ int   cnt[RANGE];
    __shared__ float deg[RANGE];
    __shared__ int   sm[RANGE];
    __shared__ int   cur[RANGE];

    const bool fit = (nE <= STAGE_CAP);

    cnt[tid] = 0;
    deg[tid] = 0.0f;
    __syncthreads();
    for (int i = tid; i < nE; i += 256) {
        int2 t = ep_tmp[base + i];
        if (fit) stage[i] = t;
        int dl = (t.x >> 17) & (RANGE - 1);
        atomicAdd(&cnt[dl], 1);
        atomicAdd(&deg[dl], __int_as_float(t.y));
    }
    __syncthreads();
    int c = cnt[tid];
    sm[tid] = c;
    __syncthreads();
#pragma unroll
    for (int o = 1; o < 256; o <<= 1) {
        int u = (tid >= o) ? sm[tid - o] : 0;
        __syncthreads();
        sm[tid] += u;
        __syncthreads();
    }
    int excl = sm[tid] - c;
    cur[tid] = base + excl;
    if (tid < nNodes) {
        rp[node0 + tid]  = base + excl;
        dis[node0 + tid] = rsqrtf(deg[tid] + 1.0f);
    }
    if (b == NBUK - 1 && tid == 0) rp[N_NODES] = N_EDGES;
    __syncthreads();
    for (int i = tid; i < nE; i += 256) {
        int2 t = fit ? stage[i] : ep_tmp[base + i];
        int dl = (t.x >> 17) & (RANGE - 1);
        int pos = atomicAdd(&cur[dl], 1);
        ep[pos] = make_int2(t.x & 0x1FFFF, t.y);       // (src, ew)
    }
}

// --- 6. window-local degree counting sort -> perm ------------------------------
// Sorts nodes by (clamped) degree WITHIN each 2048-node window. Wave degree
// uniformity == global sort (iid degrees), but rp/ep/out locality preserved.
__global__ __launch_bounds__(256) void k_wsort(const int* __restrict__ rp,
                                               int* __restrict__ perm)
{
    const int w    = blockIdx.x;
    const int tid  = threadIdx.x;
    const int node0 = w * WSIZE;
    const int nN   = min(WSIZE, N_NODES - node0);

    __shared__ int h[WBINS];
    __shared__ int base[WBINS];
    __shared__ int cur[WBINS];
    if (tid < WBINS) h[tid] = 0;
    __syncthreads();

    int mybin[WSIZE / 256];
#pragma unroll
    for (int j = 0; j < WSIZE / 256; ++j) {
        int li = tid + j * 256;
        int b = -1;
        if (li < nN) {
            int n = node0 + li;
            b = min(rp[n + 1] - rp[n], WBINS - 1);
            atomicAdd(&h[b], 1);
        }
        mybin[j] = b;
    }
    __syncthreads();
    if (tid < WBINS) {
        int s = 0;
        for (int i = 0; i < tid; ++i) s += h[i];   // 64 bins: O(64) fine
        base[tid] = s;
        cur[tid]  = 0;
    }
    __syncthreads();
#pragma unroll
    for (int j = 0; j < WSIZE / 256; ++j) {
        int b = mybin[j];
        if (b >= 0) {
            int off = atomicAdd(&cur[b], 1);
            perm[node0 + base[b] + off] = node0 + tid + j * 256;
        }
    }
}

// --- prepack W into B-fragment layout (lane l: col=l&15, k-octet=l>>4) -----------
template <int KIN, int KOUT>
__global__ __launch_bounds__(256) void k_prepack(const float* __restrict__ W,
                                                 unsigned short* __restrict__ wp)
{
    constexpr int KS = KIN / 32;
    constexpr int NSLOT = (KOUT / 16) * KS * 64;
    int idx = blockIdx.x * blockDim.x + threadIdx.x;
    if (idx >= NSLOT) return;
    int l  = idx & 63;
    int t  = idx >> 6;
    int ks = t % KS;
    int nt = t / KS;
    int col = nt * 16 + (l & 15);
    int k0  = ks * 32 + (l >> 4) * 8;
    unsigned short o[8];
#pragma unroll
    for (int j = 0; j < 8; ++j)
        o[j] = f2b(W[(k0 + j) * KOUT + col]);
    *reinterpret_cast<uint4*>(&wp[(size_t)idx * 8]) = *reinterpret_cast<uint4*>(o);
}

// --- MFMA GEMM, dis-scaled epilogue; A either fp32 (in-reg cvt) or bf16 ---------
template <int KIN, int KOUT, bool AFP32>
__global__ __launch_bounds__(256) void k_gemm_mfma(const void* __restrict__ Aptr,
                                                   const unsigned short* __restrict__ Wp,
                                                   const float* __restrict__ dis,
                                                   unsigned short* __restrict__ C)
{
    constexpr int NT = KOUT / 16;
    constexpr int KS = KIN / 32;
    const int tid  = threadIdx.x;
    const int lane = tid & 63;
    const int wave = blockIdx.x * (blockDim.x >> 6) + (tid >> 6);
    const int row0 = wave * 16;
    if (row0 >= N_NODES) return;

    f32x4 acc[NT];
#pragma unroll
    for (int nt = 0; nt < NT; ++nt)
        acc[nt] = f32x4{0.f, 0.f, 0.f, 0.f};

    const int arow = row0 + (lane & 15);
    const int koff = (lane >> 4) * 8;
#pragma unroll
    for (int ks = 0; ks < KS; ++ks) {
        bf16x8 a;
        if constexpr (AFP32) {
            const float* A = (const float*)Aptr;
            const float* p = A + (size_t)arow * KIN + ks * 32 + koff;
            float4 f0 = *reinterpret_cast<const float4*>(p);
            float4 f1 = *reinterpret_cast<const float4*>(p + 4);
            a[0] = (short)f2b(f0.x); a[1] = (short)f2b(f0.y);
            a[2] = (short)f2b(f0.z); a[3] = (short)f2b(f0.w);
            a[4] = (short)f2b(f1.x); a[5] = (short)f2b(f1.y);
            a[6] = (short)f2b(f1.z); a[7] = (short)f2b(f1.w);
        } else {
            const unsigned short* A = (const unsigned short*)Aptr;
            a = *reinterpret_cast<const bf16x8*>(A + (size_t)arow * KIN + ks * 32 + koff);
        }
#pragma unroll
        for (int nt = 0; nt < NT; ++nt) {
            bf16x8 bfr = *reinterpret_cast<const bf16x8*>(Wp + ((size_t)(nt * KS + ks) * 64 + lane) * 8);
            acc[nt] = __builtin_amdgcn_mfma_f32_16x16x32_bf16(a, bfr, acc[nt], 0, 0, 0);
        }
    }

    // C/D layout (m89-verified): col = lane&15, row = (lane>>4)*4 + r
    const int r0 = row0 + ((lane >> 4) << 2);
    const int c0 = lane & 15;
    float dv[4];
#pragma unroll
    for (int r = 0; r < 4; ++r) dv[r] = dis[r0 + r];
#pragma unroll
    for (int nt = 0; nt < NT; ++nt) {
#pragma unroll
        for (int r = 0; r < 4; ++r)
            C[(size_t)(r0 + r) * KOUT + nt * 16 + c0] = f2b(acc[nt][r] * dv[r]);
    }
}

// --- CSR gather (window-degree-sorted perm), 16B loads, fused finalize -----------
// out[n] = dis[n] * (sum_e ew_e * xws[src_e] + xws[n]) + b   (+relu / bf16 opt)
template <int DIM, bool RELU, bool OBF16>
__global__ __launch_bounds__(256) void k_gather(const int*  __restrict__ perm,
                                                const int*  __restrict__ rp,
                                                const int2* __restrict__ ep,
                                                const unsigned short* __restrict__ xws,
                                                const float* __restrict__ dis,
                                                const float* __restrict__ bias,
                                                void* __restrict__ out)
{
    constexpr int TPN = DIM / 8;          // threads per node (16 or 8)
    constexpr int NPB = 256 / TPN;        // nodes per block; N_NODES % NPB == 0
    const int tid = threadIdx.x;
    const int n   = perm[blockIdx.x * NPB + tid / TPN];
    const int d8  = tid % TPN;
    const uint4* xw8 = reinterpret_cast<const uint4*>(xws);
    const int beg = rp[n];
    const int end = rp[n + 1];

    float a0[8] = {0,0,0,0,0,0,0,0};
    float a1[8] = {0,0,0,0,0,0,0,0};

    auto fma8 = [](float w, uint4 u, float* acc) {
        acc[0] = fmaf(w, __uint_as_float(u.x << 16),          acc[0]);
        acc[1] = fmaf(w, __uint_as_float(u.x & 0xFFFF0000u),  acc[1]);
        acc[2] = fmaf(w, __uint_as_float(u.y << 16),          acc[2]);
        acc[3] = fmaf(w, __uint_as_float(u.y & 0xFFFF0000u),  acc[3]);
        acc[4] = fmaf(w, __uint_as_float(u.z << 16),          acc[4]);
        acc[5] = fmaf(w, __uint_as_float(u.z & 0xFFFF0000u),  acc[5]);
        acc[6] = fmaf(w, __uint_as_float(u.w << 16),          acc[6]);
        acc[7] = fmaf(w, __uint_as_float(u.w & 0xFFFF0000u),  acc[7]);
    };

    int i = beg;
    for (; i + 8 <= end; i += 8) {
        int2 e0 = ep[i],     e1 = ep[i + 1], e2 = ep[i + 2], e3 = ep[i + 3];
        int2 e4 = ep[i + 4], e5 = ep[i + 5], e6 = ep[i + 6], e7 = ep[i + 7];
        uint4 u0 = xw8[(size_t)e0.x * TPN + d8];
        uint4 u1 = xw8[(size_t)e1.x * TPN + d8];
        uint4 u2 = xw8[(size_t)e2.x * TPN + d8];
        uint4 u3 = xw8[(size_t)e3.x * TPN + d8];
        uint4 u4 = xw8[(size_t)e4.x * TPN + d8];
        uint4 u5 = xw8[(size_t)e5.x * TPN + d8];
        uint4 u6 = xw8[(size_t)e6.x * TPN + d8];
        uint4 u7 = xw8[(size_t)e7.x * TPN + d8];
        fma8(__int_as_float(e0.y), u0, a0);
        fma8(__int_as_float(e1.y), u1, a1);
        fma8(__int_as_float(e2.y), u2, a0);
        fma8(__int_as_float(e3.y), u3, a1);
        fma8(__int_as_float(e4.y), u4, a0);
        fma8(__int_as_float(e5.y), u5, a1);
        fma8(__int_as_float(e6.y), u6, a0);
        fma8(__int_as_float(e7.y), u7, a1);
    }
    for (; i < end; ++i) {
        int2 e = ep[i];
        uint4 u = xw8[(size_t)e.x * TPN + d8];
        fma8(__int_as_float(e.y), u, a0);
    }
    // self term: + 1.0 * xws[n]
    {
        uint4 un = xw8[(size_t)n * TPN + d8];
        fma8(1.0f, un, a0);
    }

    const float dn = dis[n];
    const float4* b4 = reinterpret_cast<const float4*>(bias);
    float4 blo = b4[d8 * 2];
    float4 bhi = b4[d8 * 2 + 1];
    float v[8];
    v[0] = fmaf(dn, a0[0] + a1[0], blo.x);
    v[1] = fmaf(dn, a0[1] + a1[1], blo.y);
    v[2] = fmaf(dn, a0[2] + a1[2], blo.z);
    v[3] = fmaf(dn, a0[3] + a1[3], blo.w);
    v[4] = fmaf(dn, a0[4] + a1[4], bhi.x);
    v[5] = fmaf(dn, a0[5] + a1[5], bhi.y);
    v[6] = fmaf(dn, a0[6] + a1[6], bhi.z);
    v[7] = fmaf(dn, a0[7] + a1[7], bhi.w);
    if (RELU) {
#pragma unroll
        for (int j = 0; j < 8; ++j) v[j] = fmaxf(v[j], 0.0f);
    }
    if (OBF16) {
        uint4 o;
        o.x = (unsigned)f2b(v[0]) | ((unsigned)f2b(v[1]) << 16);
        o.y = (unsigned)f2b(v[2]) | ((unsigned)f2b(v[3]) << 16);
        o.z = (unsigned)f2b(v[4]) | ((unsigned)f2b(v[5]) << 16);
        o.w = (unsigned)f2b(v[6]) | ((unsigned)f2b(v[7]) << 16);
        reinterpret_cast<uint4*>(out)[(size_t)n * TPN + d8] = o;
    } else {
        float4* o4 = reinterpret_cast<float4*>(out);
        o4[(size_t)n * (DIM / 4) + d8 * 2]     = make_float4(v[0], v[1], v[2], v[3]);
        o4[(size_t)n * (DIM / 4) + d8 * 2 + 1] = make_float4(v[4], v[5], v[6], v[7]);
    }
}

extern "C" void kernel_launch(void* const* d_in, const int* in_sizes, int n_in,
                              void* d_out, int out_size, void* d_ws, size_t ws_size,
                              hipStream_t stream)
{
    const float* x    = (const float*)d_in[0];
    const int*   eidx = (const int*)  d_in[1];   // [2, N_EDGES] int32
    const float* curv = (const float*)d_in[2];   // [N_EDGES, 1]
    const float* W1   = (const float*)d_in[3];
    const float* b1   = (const float*)d_in[4];
    const float* W2   = (const float*)d_in[5];
    const float* b2   = (const float*)d_in[6];
    const float* mw1  = (const float*)d_in[7];
    const float* mb1  = (const float*)d_in[8];
    const float* mw2  = (const float*)d_in[9];
    const float* mb2  = (const float*)d_in[10];

    const int* src = eidx;
    const int* dst = eidx + N_EDGES;
    float* out = (float*)d_out;

    // --- workspace carve-out (~79 MB) ---
    char*  ws  = (char*)d_ws;
    size_t off = 0;
    auto alloc = [&](size_t bytes) -> void* {
        void* p = ws + off;
        off += (bytes + 255) & ~(size_t)255;
        return p;
    };
    float* dis       = (float*)alloc(sizeof(float) * N_NODES);
    int*   rp        = (int*)  alloc(sizeof(int) * (N_NODES + 1));
    int*   gcnt      = (int*)  alloc(sizeof(int) * NBUK);                  // [zeroed]
    int*   perm      = (int*)  alloc(sizeof(int) * N_NODES);
    int*   bucketBase= (int*)  alloc(sizeof(int) * (NBUK + 1));
    int*   blockHist = (int*)  alloc(sizeof(int) * (size_t)NBUK * NPART);  // bucket-major
    int2*  ep_tmp    = (int2*) alloc(sizeof(int2) * N_EDGES);
    int2*  ep        = (int2*) alloc(sizeof(int2) * N_EDGES);              // (src, ew)
    unsigned short* xws = (unsigned short*)alloc(sizeof(unsigned short) * (size_t)N_NODES * HID_DIM);
    unsigned short* h1b = (unsigned short*)alloc(sizeof(unsigned short) * (size_t)N_NODES * HID_DIM);
    unsigned short* wp1 = (unsigned short*)alloc(sizeof(unsigned short) * (HID_DIM / 16) * (IN_DIM / 32) * 64 * 8);
    unsigned short* wp2 = (unsigned short*)alloc(sizeof(unsigned short) * (OUT_DIM / 16) * (HID_DIM / 32) * 64 * 8);

    hipMemsetAsync(gcnt, 0, sizeof(int) * NBUK, stream);

    const int B = 256;
    auto cdiv = [](long long a, long long b) { return (int)((a + b - 1) / b); };

    // CSR build via bucketed counting sort (deg/dis fused into bucket sort)
    k_hist        <<<NPART, 512, 0, stream>>>(dst, blockHist, gcnt);
    k_scan_buckets<<<1, 512, 0, stream>>>(gcnt, bucketBase);
    k_colscan     <<<NBUK, 256, 0, stream>>>(blockHist, bucketBase);
    k_partition   <<<NPART, 512, 0, stream>>>(curv, src, dst, mw1, mb1, mw2, mb2,
                                              blockHist, ep_tmp);
    k_bucket_sort <<<NBUK, 256, 0, stream>>>(ep_tmp, bucketBase, ep, rp, dis);

    // window-local degree permutation (uniform waves, locality preserved)
    k_wsort<<<cdiv(N_NODES, WSIZE), 256, 0, stream>>>(rp, perm);

    // weight prepack (tiny)
    k_prepack<IN_DIM, HID_DIM><<<cdiv((HID_DIM/16)*(IN_DIM/32)*64, B), B, 0, stream>>>(W1, wp1);
    k_prepack<HID_DIM, OUT_DIM><<<cdiv((OUT_DIM/16)*(HID_DIM/32)*64, B), B, 0, stream>>>(W2, wp2);

    const int GEMM_GRID = cdiv(N_NODES / 16, 4);   // 4 waves/block, 16 rows/wave

    // layer 1: xws1 = dis .* (x@W1)  (MFMA, fp32 A with in-reg cvt)
    k_gemm_mfma<IN_DIM, HID_DIM, true><<<GEMM_GRID, 256, 0, stream>>>(x, wp1, dis, xws);
    k_gather<HID_DIM, true, true><<<N_NODES / 16, 256, 0, stream>>>(perm, rp, ep, xws, dis, b1, h1b);

    // layer 2: xws2 = dis .* (h1@W2); out = dis*(gather+self) + b2  (fp32)
    k_gemm_mfma<HID_DIM, OUT_DIM, false><<<GEMM_GRID, 256, 0, stream>>>(h1b, wp2, dis, xws);
    k_gather<OUT_DIM, false, false><<<N_NODES / 32, 256, 0, stream>>>(perm, rp, ep, xws, dis, b2, out);
}